// Round 9
// baseline (125.118 us; speedup 1.0000x reference)
//
#include <hip/hip_runtime.h>
#include <hip/hip_fp16.h>

#define D 512
#define NTOK 512
#define BINS 64

typedef float v4f __attribute__((ext_vector_type(4)));
typedef int v4i __attribute__((ext_vector_type(4)));
typedef short short8 __attribute__((ext_vector_type(8)));
typedef _Float16 h8 __attribute__((ext_vector_type(8)));

// packed f16 tanh-approx gelu: x * sigmoid(1.5957691x + 0.0713548x^3), exp2
// form, 9 insts. f16 saturation gives correct limits: e=inf -> rcp=0 ->
// gelu=0 (x<<0); e->0 -> rcp(1)=1 -> gelu=x (x>>0).
__device__ __forceinline__ __half2 gelu2(__half2 x) {
    __half2 s = __hmul2(x, x);
    __half2 q = __hmul2(x, __hfma2(s, __float2half2_rn(-0.1029437f),
                                      __float2half2_rn(-2.3022082f)));
    __half2 e = h2exp2(q);
    __half2 r = h2rcp(__hadd2(e, __float2half2_rn(1.0f)));
    return __hmul2(x, r);
}

__device__ __forceinline__ __half2 bc_h2(int v) { return __builtin_bit_cast(__half2, v); }
__device__ __forceinline__ int bc_i(__half2 v) { return __builtin_bit_cast(int, v); }

__device__ __forceinline__ v4i pack8(v4f a, v4f b) {
    h8 o;
    o[0] = (_Float16)a.x; o[1] = (_Float16)a.y; o[2] = (_Float16)a.z; o[3] = (_Float16)a.w;
    o[4] = (_Float16)b.x; o[5] = (_Float16)b.y; o[6] = (_Float16)b.z; o[7] = (_Float16)b.w;
    return __builtin_bit_cast(v4i, o);
}

// DMA 16B global -> LDS (wave-uniform LDS base + lane*16 implicit scatter).
__device__ __forceinline__ void g2lds16(const void* g, void* l) {
    __builtin_amdgcn_global_load_lds(
        (const __attribute__((address_space(1))) void*)g,
        (__attribute__((address_space(3))) void*)l, 16, 0, 0);
}

#define WAITVM_(N) asm volatile("s_waitcnt vmcnt(" #N ")" ::: "memory")
#define WAITVM(N) WAITVM_(N)

// ---- k_pack: operand packing (unchanged).
__global__ __launch_bounds__(256) void k_pack(const float* __restrict__ x,
                                              const float* __restrict__ W1,
                                              const float* __restrict__ W2,
                                              v4i* __restrict__ Ap,
                                              v4i* __restrict__ Wp,
                                              short8* __restrict__ Bp) {
    const int b = blockIdx.x;
    const int t = threadIdx.x;
    if (b < 32) {            // x fragments: 32 rb x 16 ks x 64 lanes
        const int rb = b;
#pragma unroll
        for (int u = 0; u < 4; ++u) {
            const int e = t + 256 * u;           // 0..1023
            const int l = e & 63, ks = e >> 6;
            const float* src = x + (size_t)(rb * 16 + (l & 15)) * D + ks * 32 + (l >> 4) * 8;
            v4f a = *(const v4f*)src;
            v4f c = *(const v4f*)(src + 4);
            Ap[(size_t)(rb * 16 + ks) * 64 + l] = pack8(a, c);
        }
    } else if (b < 288) {    // W1 fragments: one slot per thread
        const int slot = (b - 32) * 256 + t;     // 0..65535
        const int l = slot & 63;
        const int ks = (slot >> 6) & 15;
        const int nb = slot >> 10;               // 0..63
        const int ng = nb * 16 + (l & 15);       // combined out col 0..1023
        const float* src = W1 + (size_t)((ng >> 9) * D + ks * 32 + (l >> 4) * 8) * D
                              + (ng & 511);
        h8 o;
#pragma unroll
        for (int j = 0; j < 8; ++j) o[j] = (_Float16)src[(size_t)j * D];  // RTE
        Wp[(size_t)(nb * 16 + ks) * 64 + l] = __builtin_bit_cast(v4i, o);
    } else {                 // W2 -> Bp
        const int tid = (b - 288) * 256 + t;     // 0..4095
        const int ll = tid & 63;
        const int nt = (tid >> 6) & 3;
        const int kt = tid >> 8;
        const int colp = nt * 16 + (ll & 15);
        const int krow = kt * 32 + (ll >> 4) * 8;
        short8 v;
#pragma unroll
        for (int u = 0; u < 8; ++u) {
            _Float16 hv = (_Float16)W2[(size_t)(krow + u) * BINS + colp];  // RTE
            v[u] = __builtin_bit_cast(short, hv);
        }
        Bp[tid] = v;
    }
}

// ---- k_gemm: projection GEMM (unchanged).
__global__ __launch_bounds__(256) void k_gemm(const v4i* __restrict__ Ap,
                                              const v4i* __restrict__ Wp,
                                              const float* __restrict__ b1,
                                              _Float16* __restrict__ hi,
                                              _Float16* __restrict__ hj) {
    const int l = threadIdx.x & 63;
    const int w = threadIdx.x >> 6;
    const int c = l & 15;
    const int q = l >> 4;
    const int mb = blockIdx.x >> 4;              // 0..31
    const int cb = blockIdx.x & 15;
    const int nb = cb * 4 + w;

    const v4i* ap = Ap + (size_t)mb * 16 * 64 + l;
    const v4i* wp = Wp + (size_t)nb * 16 * 64 + l;

    v4f acc = {0.f, 0.f, 0.f, 0.f};
#pragma unroll
    for (int ks = 0; ks < 16; ++ks) {
        v4i a0 = ap[ks * 64];
        v4i bb = wp[ks * 64];
        acc = __builtin_amdgcn_mfma_f32_16x16x32_f16(__builtin_bit_cast(h8, a0),
                                                     __builtin_bit_cast(h8, bb), acc, 0, 0, 0);
    }

    const int ng = nb * 16 + c;
    const float b1v = (ng < D) ? b1[ng] : 0.0f;
    _Float16* dst = (ng < D ? hi : hj) + (ng & 511);
    const int row0 = mb * 16 + q * 4;
#pragma unroll
    for (int r = 0; r < 4; ++r)
        dst[(size_t)(row0 + r) * D] = (_Float16)(acc[r] + b1v);
}

// ---- k_main: counted-vmcnt DMA pipeline, 6 blocks/CU round.
// Grid 2048 = 64 i-tiles (8 rows) x 32 j-tiles (16 cols); wave w owns 2 i-rows
// (acc[2][4]: 32 AGPR + ~36 arch = ~68 unified regs <= 85-cap at (256,6)).
// Per-kt buffer 5.5KB {Bp 4K | hj 1K | hi 0.5K}, NBUF=4 ring = 22KB LDS ->
// 6 blocks/CU (132KB). 6 waves/SIMD fill the issue holes that capped r8 at
// ~47% VALU efficiency (4 phase-correlated waves/SIMD). Total gelu work
// unchanged (split along i); Bp/hj L2 re-reads ~3TB/s << 34TB/s ceiling.
// Ring safety: buf for tile kt+2 (index (kt+2)%4) last read by compute(kt-2),
// finished by all waves before barrier(kt-1), which the stager passed.
#define NBUF 4
#define BUFSZ 5632
__global__ __launch_bounds__(256, 6) void k_main(const __half* __restrict__ hi,
                                                 const __half* __restrict__ hj,
                                                 const float* __restrict__ b2,
                                                 const char* __restrict__ BpB,
                                                 float* __restrict__ out) {
    const int l = threadIdx.x & 63;
    const int w = threadIdx.x >> 6;
    const int c = l & 15;   // MFMA col: A m-index (j-offset) / B,D n-offset
    const int q = l >> 4;   // quad: k-group for A/B, row-group for D
    const int ib = (blockIdx.x >> 5) * 8;
    const int j0 = (blockIdx.x & 31) * 16;

    __shared__ __align__(16) char lds[NBUF * BUFSZ];   // 22528 B

    const char* hjB = (const char*)hj;
    const char* hiB = (const char*)hi;

    // stage tile kt into ring buffer bi: wave w -> Bp slots w*64.., 16B/lane.
    // wave 0 also stages hj (lane l <-> row j0+(l&15), 16B unit (l>>4));
    // wave 1 lanes 0..31 stage hi (row ib+(l>>2), 16B unit (l&3)).
#define STAGE(kt_, bi_)                                                          \
    {                                                                            \
        char* buf_ = lds + (bi_) * BUFSZ;                                        \
        g2lds16(BpB + (size_t)(kt_) * 4096 + (w * 64 + l) * 16, buf_ + w * 1024);\
        if (w == 0)                                                              \
            g2lds16(hjB + (size_t)(j0 + (l & 15)) * 1024 + (kt_) * 64 + (l >> 4) * 16, \
                    buf_ + 4096);                                                \
        if (w == 1 && l < 32)                                                    \
            g2lds16(hiB + (size_t)(ib + (l >> 2)) * 1024 + (kt_) * 64 + (l & 3) * 16,  \
                    buf_ + 5120);                                                \
    }

    v4f acc[2][4] = {};  // [p(i)][nt]

    STAGE(0, 0) STAGE(1, 1)

#pragma unroll
    for (int kt = 0; kt < 16; ++kt) {
        if (kt + 2 < 16) STAGE(kt + 2, (kt + 2) % NBUF)
        const int rem = (kt <= 13) ? 2 : 15 - kt;   // stage-groups in flight after kt's
        if (w < 2) {
            if (rem == 2) WAITVM(4); else if (rem == 1) WAITVM(2); else WAITVM(0);
        } else {
            if (rem == 2) WAITVM(2); else if (rem == 1) WAITVM(1); else WAITVM(0);
        }
        __builtin_amdgcn_s_barrier();

        const char* buf = lds + (kt % NBUF) * BUFSZ;
        const v4i* bsec = (const v4i*)buf;               // Bp: slot nt*64 + l
        v4i bfr[4];
#pragma unroll
        for (int nt = 0; nt < 4; ++nt) bfr[nt] = bsec[nt * 64 + l];
        v4i hjraw = ((const v4i*)(buf + 4096))[l];
        __half2 j0h = bc_h2(hjraw.x), j1h = bc_h2(hjraw.y);
        __half2 j2h = bc_h2(hjraw.z), j3h = bc_h2(hjraw.w);
#pragma unroll
        for (int p = 0; p < 2; ++p) {
            v4i ar = *(const v4i*)(buf + 5120 + ((w * 2 + p) * 4 + q) * 16);
            __half2 g0 = gelu2(__hadd2(bc_h2(ar.x), j0h));
            __half2 g1 = gelu2(__hadd2(bc_h2(ar.y), j1h));
            __half2 g2 = gelu2(__hadd2(bc_h2(ar.z), j2h));
            __half2 g3 = gelu2(__hadd2(bc_h2(ar.w), j3h));
            v4i ai = {bc_i(g0), bc_i(g1), bc_i(g2), bc_i(g3)};
            h8 af = __builtin_bit_cast(h8, ai);
#pragma unroll
            for (int nt = 0; nt < 4; ++nt)
                acc[p][nt] = __builtin_amdgcn_mfma_f32_16x16x32_f16(
                    af, __builtin_bit_cast(h8, bfr[nt]), acc[p][nt], 0, 0, 0);
        }
    }
#undef STAGE

    const int i0 = ib + w * 2;
#pragma unroll
    for (int p = 0; p < 2; ++p) {
        const size_t rowbase = ((size_t)(i0 + p) * NTOK + j0 + q * 4) * BINS;
#pragma unroll
        for (int nt = 0; nt < 4; ++nt) {
            const float bb = b2[nt * 16 + c];
            float* op = out + rowbase + nt * 16 + c;
#pragma unroll
            for (int rr = 0; rr < 4; ++rr)
                op[(size_t)rr * BINS] = acc[p][nt][rr] + bb;
        }
    }
}

extern "C" void kernel_launch(void* const* d_in, const int* in_sizes, int n_in,
                              void* d_out, int out_size, void* d_ws, size_t ws_size,
                              hipStream_t stream) {
    const float* x  = (const float*)d_in[0];
    const float* W1 = (const float*)d_in[1];
    const float* b1 = (const float*)d_in[2];
    const float* W2 = (const float*)d_in[3];
    const float* b2 = (const float*)d_in[4];
    float* out = (float*)d_out;

    char* ws = (char*)d_ws;
    __half* hi = (__half*)ws;                          // 512 KB
    __half* hj = (__half*)(ws + (512u << 10));         // 512 KB
    short8* Bp = (short8*)(ws + (1u << 20));           // 64 KB
    v4i*    Ap = (v4i*)(ws + (1u << 20) + (64u << 10));            // 512 KB
    v4i*    Wp = (v4i*)(ws + (1u << 20) + (64u << 10) + (512u << 10));  // 1 MB

    k_pack<<<304, 256, 0, stream>>>(x, W1, W2, Ap, Wp, Bp);
    k_gemm<<<512, 256, 0, stream>>>(Ap, Wp, b1, (_Float16*)hi, (_Float16*)hj);
    k_main<<<2048, 256, 0, stream>>>(hi, hj, b2, (const char*)Bp, out);
}

// Round 10
// 122.826 us; speedup vs baseline: 1.0187x; 1.0187x over previous
//
#include <hip/hip_runtime.h>
#include <hip/hip_fp16.h>

#define D 512
#define NTOK 512
#define BINS 64

typedef float v4f __attribute__((ext_vector_type(4)));
typedef int v4i __attribute__((ext_vector_type(4)));
typedef short short8 __attribute__((ext_vector_type(8)));
typedef _Float16 h8 __attribute__((ext_vector_type(8)));

// packed f16 tanh-approx gelu: x * sigmoid(1.5957691x + 0.0713548x^3), exp2
// form, 9 insts. f16 saturation gives correct limits: e=inf -> rcp=0 ->
// gelu=0 (x<<0); e->0 -> rcp(1)=1 -> gelu=x (x>>0).
__device__ __forceinline__ __half2 gelu2(__half2 x) {
    __half2 s = __hmul2(x, x);
    __half2 q = __hmul2(x, __hfma2(s, __float2half2_rn(-0.1029437f),
                                      __float2half2_rn(-2.3022082f)));
    __half2 e = h2exp2(q);
    __half2 r = h2rcp(__hadd2(e, __float2half2_rn(1.0f)));
    return __hmul2(x, r);
}

__device__ __forceinline__ __half2 bc_h2(int v) { return __builtin_bit_cast(__half2, v); }
__device__ __forceinline__ int bc_i(__half2 v) { return __builtin_bit_cast(int, v); }

__device__ __forceinline__ v4i pack8(v4f a, v4f b) {
    h8 o;
    o[0] = (_Float16)a.x; o[1] = (_Float16)a.y; o[2] = (_Float16)a.z; o[3] = (_Float16)a.w;
    o[4] = (_Float16)b.x; o[5] = (_Float16)b.y; o[6] = (_Float16)b.z; o[7] = (_Float16)b.w;
    return __builtin_bit_cast(v4i, o);
}

// DMA 16B global -> LDS (wave-uniform LDS base + lane*16 implicit scatter).
__device__ __forceinline__ void g2lds16(const void* g, void* l) {
    __builtin_amdgcn_global_load_lds(
        (const __attribute__((address_space(1))) void*)g,
        (__attribute__((address_space(3))) void*)l, 16, 0, 0);
}

#define WAITVM_(N) asm volatile("s_waitcnt vmcnt(" #N ")" ::: "memory")
#define WAITVM(N) WAITVM_(N)

// ---- k_pack: operand packing (unchanged from r8).
__global__ __launch_bounds__(256) void k_pack(const float* __restrict__ x,
                                              const float* __restrict__ W1,
                                              const float* __restrict__ W2,
                                              v4i* __restrict__ Ap,
                                              v4i* __restrict__ Wp,
                                              short8* __restrict__ Bp) {
    const int b = blockIdx.x;
    const int t = threadIdx.x;
    if (b < 32) {            // x fragments: 32 rb x 16 ks x 64 lanes
        const int rb = b;
#pragma unroll
        for (int u = 0; u < 4; ++u) {
            const int e = t + 256 * u;           // 0..1023
            const int l = e & 63, ks = e >> 6;
            const float* src = x + (size_t)(rb * 16 + (l & 15)) * D + ks * 32 + (l >> 4) * 8;
            v4f a = *(const v4f*)src;
            v4f c = *(const v4f*)(src + 4);
            Ap[(size_t)(rb * 16 + ks) * 64 + l] = pack8(a, c);
        }
    } else if (b < 288) {    // W1 fragments: one slot per thread
        const int slot = (b - 32) * 256 + t;     // 0..65535
        const int l = slot & 63;
        const int ks = (slot >> 6) & 15;
        const int nb = slot >> 10;               // 0..63
        const int ng = nb * 16 + (l & 15);       // combined out col 0..1023
        const float* src = W1 + (size_t)((ng >> 9) * D + ks * 32 + (l >> 4) * 8) * D
                              + (ng & 511);
        h8 o;
#pragma unroll
        for (int j = 0; j < 8; ++j) o[j] = (_Float16)src[(size_t)j * D];  // RTE
        Wp[(size_t)(nb * 16 + ks) * 64 + l] = __builtin_bit_cast(v4i, o);
    } else {                 // W2 -> Bp
        const int tid = (b - 288) * 256 + t;     // 0..4095
        const int ll = tid & 63;
        const int nt = (tid >> 6) & 3;
        const int kt = tid >> 8;
        const int colp = nt * 16 + (ll & 15);
        const int krow = kt * 32 + (ll >> 4) * 8;
        short8 v;
#pragma unroll
        for (int u = 0; u < 8; ++u) {
            _Float16 hv = (_Float16)W2[(size_t)(krow + u) * BINS + colp];  // RTE
            v[u] = __builtin_bit_cast(short, hv);
        }
        Bp[tid] = v;
    }
}

// ---- k_gemm: projection GEMM (unchanged from r8).
__global__ __launch_bounds__(256) void k_gemm(const v4i* __restrict__ Ap,
                                              const v4i* __restrict__ Wp,
                                              const float* __restrict__ b1,
                                              _Float16* __restrict__ hi,
                                              _Float16* __restrict__ hj) {
    const int l = threadIdx.x & 63;
    const int w = threadIdx.x >> 6;
    const int c = l & 15;
    const int q = l >> 4;
    const int mb = blockIdx.x >> 4;              // 0..31
    const int cb = blockIdx.x & 15;
    const int nb = cb * 4 + w;

    const v4i* ap = Ap + (size_t)mb * 16 * 64 + l;
    const v4i* wp = Wp + (size_t)nb * 16 * 64 + l;

    v4f acc = {0.f, 0.f, 0.f, 0.f};
#pragma unroll
    for (int ks = 0; ks < 16; ++ks) {
        v4i a0 = ap[ks * 64];
        v4i bb = wp[ks * 64];
        acc = __builtin_amdgcn_mfma_f32_16x16x32_f16(__builtin_bit_cast(h8, a0),
                                                     __builtin_bit_cast(h8, bb), acc, 0, 0, 0);
    }

    const int ng = nb * 16 + c;
    const float b1v = (ng < D) ? b1[ng] : 0.0f;
    _Float16* dst = (ng < D ? hi : hj) + (ng & 511);
    const int row0 = mb * 16 + q * 4;
#pragma unroll
    for (int r = 0; r < 4; ++r)
        dst[(size_t)(row0 + r) * D] = (_Float16)(acc[r] + b1v);
}

// ---- k_main: r8 base (16x16 tile, acc[4][4], grid 1024, 4 blocks/CU) with
// 2-kt barrier phases. r9's lesson: famine is barrier-phase quantization —
// halving work/barrier cost 1.6x; so go the other way: 8 fat phases, 2 kt
// tiles each, 2x compute per barrier. NBUF=6 (36KB ring, 4 blocks = 144KB)
// preserves counted-vmcnt: phase ph stages tiles kt0+2,kt0+3 into slots
// (mod 6) last read in phase ph-2 — separated by barrier ph-1 (same safety
// invariant as r8). Per-phase wait vmcnt(4)/(2) (w<2 / w>=2), 0 only at tail.
#define NBUF 6
#define BUFSZ 6144
__global__ __launch_bounds__(256, 4) void k_main(const __half* __restrict__ hi,
                                                 const __half* __restrict__ hj,
                                                 const float* __restrict__ b2,
                                                 const char* __restrict__ BpB,
                                                 float* __restrict__ out) {
    const int l = threadIdx.x & 63;
    const int w = threadIdx.x >> 6;
    const int c = l & 15;   // MFMA col: A m-index (j-offset) / B,D n-offset
    const int q = l >> 4;   // quad: k-group for A/B, row-group for D
    const int ib = (blockIdx.x >> 5) * 16;
    const int j0 = (blockIdx.x & 31) * 16;

    __shared__ __align__(16) char lds[NBUF * BUFSZ];   // 36864 B

    const char* hjB = (const char*)hj;
    const char* hiB = (const char*)hi;

    // stage tile kt into ring buffer bi: wave w -> Bp slots w*64.., 16B/lane.
    // wave 0 also stages hj (lane l <-> row j0+(l&15), 16B unit (l>>4));
    // wave 1 stages hi (lane l <-> row ib+(l>>2), 16B unit (l&3)).
#define STAGE(kt_, bi_)                                                          \
    {                                                                            \
        char* buf_ = lds + (bi_) * BUFSZ;                                        \
        g2lds16(BpB + (size_t)(kt_) * 4096 + (w * 64 + l) * 16, buf_ + w * 1024);\
        if (w == 0)                                                              \
            g2lds16(hjB + (size_t)(j0 + (l & 15)) * 1024 + (kt_) * 64 + (l >> 4) * 16, \
                    buf_ + 4096);                                                \
        if (w == 1)                                                              \
            g2lds16(hiB + (size_t)(ib + (l >> 2)) * 1024 + (kt_) * 64 + (l & 3) * 16,  \
                    buf_ + 5120);                                                \
    }

    v4f acc[4][4] = {};  // [p(i)][nt]

    STAGE(0, 0) STAGE(1, 1)

#pragma unroll
    for (int ph = 0; ph < 8; ++ph) {
        const int kt0 = ph * 2;
        if (ph < 7) { STAGE(kt0 + 2, (kt0 + 2) % NBUF) STAGE(kt0 + 3, (kt0 + 3) % NBUF) }
        if (ph < 7) {
            if (w < 2) WAITVM(4); else WAITVM(2);
        } else {
            WAITVM(0);
        }
        __builtin_amdgcn_s_barrier();

#pragma unroll
        for (int kk = 0; kk < 2; ++kk) {
            const int kt = kt0 + kk;
            const char* buf = lds + (kt % NBUF) * BUFSZ;
            const v4i* bsec = (const v4i*)buf;           // Bp: slot nt*64 + l
            v4i bfr[4];
#pragma unroll
            for (int nt = 0; nt < 4; ++nt) bfr[nt] = bsec[nt * 64 + l];
            v4i hjraw = ((const v4i*)(buf + 4096))[l];
            __half2 j0h = bc_h2(hjraw.x), j1h = bc_h2(hjraw.y);
            __half2 j2h = bc_h2(hjraw.z), j3h = bc_h2(hjraw.w);
#pragma unroll
            for (int p = 0; p < 4; ++p) {
                v4i ar = *(const v4i*)(buf + 5120 + ((w * 4 + p) * 4 + q) * 16);
                __half2 g0 = gelu2(__hadd2(bc_h2(ar.x), j0h));
                __half2 g1 = gelu2(__hadd2(bc_h2(ar.y), j1h));
                __half2 g2 = gelu2(__hadd2(bc_h2(ar.z), j2h));
                __half2 g3 = gelu2(__hadd2(bc_h2(ar.w), j3h));
                v4i ai = {bc_i(g0), bc_i(g1), bc_i(g2), bc_i(g3)};
                h8 af = __builtin_bit_cast(h8, ai);
#pragma unroll
                for (int nt = 0; nt < 4; ++nt)
                    acc[p][nt] = __builtin_amdgcn_mfma_f32_16x16x32_f16(
                        af, __builtin_bit_cast(h8, bfr[nt]), acc[p][nt], 0, 0, 0);
            }
        }
    }
#undef STAGE

    const int i0 = ib + w * 4;
#pragma unroll
    for (int p = 0; p < 4; ++p) {
        const size_t rowbase = ((size_t)(i0 + p) * NTOK + j0 + q * 4) * BINS;
#pragma unroll
        for (int nt = 0; nt < 4; ++nt) {
            const float bb = b2[nt * 16 + c];
            float* op = out + rowbase + nt * 16 + c;
#pragma unroll
            for (int rr = 0; rr < 4; ++rr)
                op[(size_t)rr * BINS] = acc[p][nt][rr] + bb;
        }
    }
}

extern "C" void kernel_launch(void* const* d_in, const int* in_sizes, int n_in,
                              void* d_out, int out_size, void* d_ws, size_t ws_size,
                              hipStream_t stream) {
    const float* x  = (const float*)d_in[0];
    const float* W1 = (const float*)d_in[1];
    const float* b1 = (const float*)d_in[2];
    const float* W2 = (const float*)d_in[3];
    const float* b2 = (const float*)d_in[4];
    float* out = (float*)d_out;

    char* ws = (char*)d_ws;
    __half* hi = (__half*)ws;                          // 512 KB
    __half* hj = (__half*)(ws + (512u << 10));         // 512 KB
    short8* Bp = (short8*)(ws + (1u << 20));           // 64 KB
    v4i*    Ap = (v4i*)(ws + (1u << 20) + (64u << 10));            // 512 KB
    v4i*    Wp = (v4i*)(ws + (1u << 20) + (64u << 10) + (512u << 10));  // 1 MB

    k_pack<<<304, 256, 0, stream>>>(x, W1, W2, Ap, Wp, Bp);
    k_gemm<<<512, 256, 0, stream>>>(Ap, Wp, b1, (_Float16*)hi, (_Float16*)hj);
    k_main<<<1024, 256, 0, stream>>>(hi, hj, b2, (const char*)Bp, out);
}